// Round 1
// baseline (36303.174 us; speedup 1.0000x reference)
//
#include <hip/hip_runtime.h>

#define RK 16          // workgroups per LSTM direction
#define RTH 512        // threads per recurrence WG
#define SEQ 4096
#define HID 512
#define NT 24

__device__ __forceinline__ float sigf(float x) { return 1.f / (1.f + __expf(-x)); }

// ---------------- init: zero sync counters + embedding gather ----------------
__global__ __launch_bounds__(64)
void init_gather(const float* __restrict__ emb, const int* __restrict__ sent,
                 float* __restrict__ X0, unsigned int* __restrict__ cnt)
{
    const int b = blockIdx.x, tid = threadIdx.x;
    if (b < 256) cnt[b * 64 + tid] = 0u;           // 16384 counters
    const size_t row = (size_t)sent[b] * 300;
    for (int e = tid; e < 300; e += 64)
        X0[(size_t)b * 300 + e] = emb[row + e];
}

// ---------------- fp32 GEMM: C[M,N] = A[M,K] @ W[N,K]^T + bias[N] ----------------
__global__ __launch_bounds__(256)
void sgemm_bias(const float* __restrict__ A, const float* __restrict__ W,
                const float* __restrict__ bias, float* __restrict__ C,
                int M, int N, int K)
{
    __shared__ float As[8][128];
    __shared__ float Ws[8][128];
    const int tid = threadIdx.x;
    const int m0 = blockIdx.y * 128, n0 = blockIdx.x * 128;
    const int tx = tid & 15, ty = tid >> 4;
    const int lr = tid >> 1, lk = (tid & 1) * 4;
    float acc[8][8] = {};
    for (int k0 = 0; k0 < K; k0 += 8) {
#pragma unroll
        for (int u = 0; u < 4; ++u) {
            const int k = k0 + lk + u;
            As[lk + u][lr] = (k < K) ? A[(size_t)(m0 + lr) * K + k] : 0.f;
            Ws[lk + u][lr] = (k < K) ? W[(size_t)(n0 + lr) * K + k] : 0.f;
        }
        __syncthreads();
#pragma unroll
        for (int kk = 0; kk < 8; ++kk) {
            float a[8], b[8];
#pragma unroll
            for (int i = 0; i < 8; ++i) a[i] = As[kk][ty * 8 + i];
#pragma unroll
            for (int i = 0; i < 8; ++i) b[i] = Ws[kk][tx * 8 + i];
#pragma unroll
            for (int i = 0; i < 8; ++i)
#pragma unroll
                for (int j = 0; j < 8; ++j) acc[i][j] += a[i] * b[j];
        }
        __syncthreads();
    }
#pragma unroll
    for (int i = 0; i < 8; ++i) {
        const int m = m0 + ty * 8 + i;
#pragma unroll
        for (int j = 0; j < 8; ++j) {
            const int n = n0 + tx * 8 + j;
            C[(size_t)m * N + n] = acc[i][j] + bias[n];
        }
    }
}

// ---------------- LSTM recurrence: both directions of one layer ----------------
// grid = 32 WGs (16 per direction), 512 threads. Weight rows in registers.
__global__ __launch_bounds__(RTH, 2)
void lstm_rec(const float* __restrict__ pre_f, const float* __restrict__ pre_b,
              const float* __restrict__ whh_f, const float* __restrict__ whh_b,
              float* __restrict__ out,           // (4096 x 1024): fwd cols [0,512), bwd [512,1024)
              float* __restrict__ hbuf,          // 2 x 512
              unsigned int* __restrict__ cnt)    // 2 x 4096, pre-zeroed
{
    const int g = blockIdx.x;
    const int dir = g / RK, slot = g % RK;
    const float* pre = dir ? pre_b : pre_f;
    const float* whh = dir ? whh_b : whh_f;
    float* hg = hbuf + dir * HID;
    unsigned int* c_arr = cnt + dir * SEQ;

    const int tid = threadIdx.x;
    // wave-uniform quarter index q; row r in [0,128)
    const int q = (tid >> 6) & 3;
    const int r = (tid & 63) | ((tid >> 8) << 6);
    const int gate = r >> 5, jl = r & 31;
    const int grow = gate * HID + slot * 32 + jl;  // row of W_hh / pre, in [0,2048)

    // preload 128 weights (quarter of the 512-row) into registers
    float w[128];
    {
        const float4* wp = (const float4*)(whh + (size_t)grow * HID + q * 128);
#pragma unroll
        for (int i = 0; i < 32; ++i) {
            const float4 v = wp[i];
            w[4 * i + 0] = v.x; w[4 * i + 1] = v.y; w[4 * i + 2] = v.z; w[4 * i + 3] = v.w;
        }
    }

    __shared__ float h_sm[HID];
    __shared__ float zpart[128][5];   // +1 pad breaks bank conflict on q
    __shared__ float zrow[128];
    float c_state = 0.f;

    h_sm[tid >= HID ? 0 : tid] = 0.f;   // tid<512 covers all; (guard is vestigial)
    __syncthreads();

    for (int t = 0; t < SEQ; ++t) {
        const int tt = dir ? (SEQ - 1 - t) : t;
        float pre_v = 0.f;
        if (q == 0) pre_v = pre[(size_t)tt * 2048 + grow];   // issued early, used after loop

        // partial dot: w[0:128] . h_sm[q*128 : q*128+128]  (wave-uniform LDS broadcast)
        float acc = 0.f;
        const float4* hp = (const float4*)(h_sm + q * 128);
#pragma unroll
        for (int i = 0; i < 32; ++i) {
            const float4 hv = hp[i];
            acc += w[4 * i + 0] * hv.x + w[4 * i + 1] * hv.y
                 + w[4 * i + 2] * hv.z + w[4 * i + 3] * hv.w;
        }
        zpart[r][q] = acc;
        __syncthreads();

        if (q == 0) {
            zrow[r] = zpart[r][0] + zpart[r][1] + zpart[r][2] + zpart[r][3] + pre_v;
        }
        __syncthreads();

        if (tid < 32) {
            const int j = tid;
            const float zi = zrow[j], zf = zrow[32 + j], zg = zrow[64 + j], zo = zrow[96 + j];
            const float ig = sigf(zi), fg = sigf(zf), og = sigf(zo);
            c_state = fg * c_state + ig * tanhf(zg);
            const float h = og * tanhf(c_state);
            out[(size_t)tt * 1024 + dir * HID + slot * 32 + j] = h;
            __hip_atomic_store(hg + slot * 32 + j, h, __ATOMIC_RELAXED, __HIP_MEMORY_SCOPE_AGENT);
        }
        if (tid == 0) {
            __builtin_amdgcn_fence(__ATOMIC_RELEASE, "agent");
            __hip_atomic_fetch_add(&c_arr[t], 1u, __ATOMIC_RELAXED, __HIP_MEMORY_SCOPE_AGENT);
            while (__hip_atomic_load(&c_arr[t], __ATOMIC_RELAXED, __HIP_MEMORY_SCOPE_AGENT) < (unsigned)RK) {}
            __builtin_amdgcn_fence(__ATOMIC_ACQUIRE, "agent");
        }
        __syncthreads();
        __builtin_amdgcn_fence(__ATOMIC_ACQUIRE, "agent");
        h_sm[tid] = __hip_atomic_load(hg + tid, __ATOMIC_RELAXED, __HIP_MEMORY_SCOPE_AGENT);
        __syncthreads();
    }
}

// ---------------- emissions: EM[4096,24] = X2[4096,1024] @ Wo[24,1024]^T + bo ----------------
__global__ __launch_bounds__(256)
void emissions_kernel(const float* __restrict__ X, const float* __restrict__ Wo,
                      const float* __restrict__ bo, float* __restrict__ EM)
{
    __shared__ float xs[1024];
    __shared__ float red[NT][9];
    const int t = blockIdx.x, tid = threadIdx.x;
    for (int i = tid; i < 1024; i += 256) xs[i] = X[(size_t)t * 1024 + i];
    __syncthreads();
    const int col = tid >> 3, s = tid & 7;
    if (col < NT) {
        float acc = 0.f;
        const float* wr = Wo + (size_t)col * 1024 + s * 128;
        const float* xp = xs + s * 128;
#pragma unroll 8
        for (int i = 0; i < 128; ++i) acc += wr[i] * xp[i];
        red[col][s] = acc;
    }
    __syncthreads();
    if (tid < NT) {
        float rsum = 0.f;
#pragma unroll
        for (int s2 = 0; s2 < 8; ++s2) rsum += red[tid][s2];
        EM[t * NT + tid] = rsum + bo[tid];
    }
}

// ---------------- numerator ----------------
__global__ __launch_bounds__(256)
void num_kernel(const float* __restrict__ EM, const int* __restrict__ tags,
                const float* __restrict__ stt, const float* __restrict__ ent,
                const float* __restrict__ tr, float* __restrict__ numout)
{
    __shared__ float red[256];
    const int tid = threadIdx.x;
    float acc = 0.f;
    for (int t = tid; t < SEQ; t += 256) {
        const int tg = tags[t];
        acc += EM[t * NT + tg];
        if (t < SEQ - 1) acc += tr[tg * NT + tags[t + 1]];
    }
    red[tid] = acc; __syncthreads();
    for (int s = 128; s > 0; s >>= 1) { if (tid < s) red[tid] += red[tid + s]; __syncthreads(); }
    if (tid == 0) numout[0] = red[0] + stt[tags[0]] + ent[tags[SEQ - 1]];
}

// ---------------- CRF stage 1: chunk products of M_t (t=1..4095), 16 per chunk ----------------
__global__ __launch_bounds__(576)
void crf_stage1(const float* __restrict__ EM, const float* __restrict__ trans,
                float* __restrict__ CH)
{
    __shared__ float tr[NT][NT];
    __shared__ float cur[2][NT][NT + 1];
    const int tid = threadIdx.x;
    const int i = tid / NT, j = tid % NT;
    const int c = blockIdx.x;
    const int t0 = 1 + c * 16;
    const int cm = min(16, SEQ - t0);
    const float trv = trans[i * NT + j];
    tr[i][j] = trv;
    cur[0][i][j] = trv + EM[t0 * NT + j];
    __syncthreads();
    int pp = 0;
    for (int s = 1; s < cm; ++s) {
        const float e = EM[(t0 + s) * NT + j];
        float m = -1e30f;
#pragma unroll
        for (int k = 0; k < NT; ++k) m = fmaxf(m, cur[pp][i][k] + tr[k][j]);
        float sum = 0.f;
#pragma unroll
        for (int k = 0; k < NT; ++k) sum += __expf(cur[pp][i][k] + tr[k][j] - m);
        cur[1 - pp][i][j] = m + __logf(sum) + e;
        pp = 1 - pp;
        __syncthreads();
    }
    CH[(size_t)c * 576 + i * NT + j] = cur[pp][i][j];
}

// ---------------- CRF combine: block c folds IN[c*per .. c*per+per) in order ----------------
__global__ __launch_bounds__(576)
void crf_combine(const float* __restrict__ IN, float* __restrict__ OUT, int per)
{
    __shared__ float cur[2][NT][NT + 1];
    const int tid = threadIdx.x;
    const int i = tid / NT, j = tid % NT;
    const int c = blockIdx.x;
    const float* base = IN + (size_t)c * per * 576;
    cur[0][i][j] = base[i * NT + j];
    __syncthreads();
    int pp = 0;
    for (int s = 1; s < per; ++s) {
        const float* B = base + (size_t)s * 576;
        float m = -1e30f;
#pragma unroll
        for (int k = 0; k < NT; ++k) m = fmaxf(m, cur[pp][i][k] + B[k * NT + j]);
        float sum = 0.f;
#pragma unroll
        for (int k = 0; k < NT; ++k) sum += __expf(cur[pp][i][k] + B[k * NT + j] - m);
        cur[1 - pp][i][j] = m + __logf(sum);
        pp = 1 - pp;
        __syncthreads();
    }
    OUT[(size_t)c * 576 + i * NT + j] = cur[pp][i][j];
}

// ---------------- CRF final: fold 16 partials, den, out = den - num ----------------
__global__ __launch_bounds__(576)
void crf_final(const float* __restrict__ P2, const float* __restrict__ EM,
               const float* __restrict__ stt, const float* __restrict__ ent,
               const float* __restrict__ numptr, float* __restrict__ outp)
{
    __shared__ float cur[2][NT][NT + 1];
    __shared__ float red[1024];
    const int tid = threadIdx.x;
    const int i = tid / NT, j = tid % NT;
    cur[0][i][j] = P2[i * NT + j];
    __syncthreads();
    int pp = 0;
    for (int s = 1; s < 16; ++s) {
        const float* B = P2 + (size_t)s * 576;
        float m = -1e30f;
#pragma unroll
        for (int k = 0; k < NT; ++k) m = fmaxf(m, cur[pp][i][k] + B[k * NT + j]);
        float sum = 0.f;
#pragma unroll
        for (int k = 0; k < NT; ++k) sum += __expf(cur[pp][i][k] + B[k * NT + j] - m);
        cur[1 - pp][i][j] = m + __logf(sum);
        pp = 1 - pp;
        __syncthreads();
    }
    const float v = stt[i] + EM[i] + cur[pp][i][j] + ent[j];
    red[tid] = v;
    for (int t2 = tid + 576; t2 < 1024; t2 += 576) red[t2] = -1e30f;
    __syncthreads();
    for (int s2 = 512; s2 > 0; s2 >>= 1) {
        if (tid < s2) red[tid] = fmaxf(red[tid], red[tid + s2]);
        __syncthreads();
    }
    const float m = red[0];
    __syncthreads();
    red[tid] = __expf(v - m);
    for (int t2 = tid + 576; t2 < 1024; t2 += 576) red[t2] = 0.f;
    __syncthreads();
    for (int s2 = 512; s2 > 0; s2 >>= 1) {
        if (tid < s2) red[tid] += red[tid + s2];
        __syncthreads();
    }
    if (tid == 0) outp[0] = m + __logf(red[0]) - numptr[0];
}

// ---------------- launcher ----------------
extern "C" void kernel_launch(void* const* d_in, const int* in_sizes, int n_in,
                              void* d_out, int out_size, void* d_ws, size_t ws_size,
                              hipStream_t stream)
{
    const float* emb    = (const float*)d_in[0];
    const float* wih0f  = (const float*)d_in[1];
    const float* whh0f  = (const float*)d_in[2];
    const float* b0f    = (const float*)d_in[3];
    const float* wih0b  = (const float*)d_in[4];
    const float* whh0b  = (const float*)d_in[5];
    const float* b0b    = (const float*)d_in[6];
    const float* wih1f  = (const float*)d_in[7];
    const float* whh1f  = (const float*)d_in[8];
    const float* b1f    = (const float*)d_in[9];
    const float* wih1b  = (const float*)d_in[10];
    const float* whh1b  = (const float*)d_in[11];
    const float* b1b    = (const float*)d_in[12];
    const float* wout   = (const float*)d_in[13];
    const float* bout   = (const float*)d_in[14];
    const float* sttr   = (const float*)d_in[15];
    const float* entr   = (const float*)d_in[16];
    const float* trans  = (const float*)d_in[17];
    const int*   sent   = (const int*)d_in[18];
    const int*   tags   = (const int*)d_in[19];

    float* ws = (float*)d_ws;
    float* X0   = ws;                          // 4096*300
    float* PRE  = X0 + 1228800;                // 2 * 4096*2048
    float* X1   = PRE + 16777216;              // 4096*1024
    float* X2   = X1 + 4194304;                // 4096*1024
    float* EMb  = X2 + 4194304;                // 4096*24
    float* CH   = EMb + 98304;                 // 256*576
    float* P2   = CH + 147456;                 // 16*576
    float* NUMv = P2 + 9216;                   // 1 (padded 64)
    float* HBUF = NUMv + 64;                   // 4*512
    unsigned int* CNT = (unsigned int*)(HBUF + 2048); // 4*4096

    const int PREST = 8388608; // per-direction stride in PRE

    init_gather<<<4096, 64, 0, stream>>>(emb, sent, X0, CNT);

    dim3 gg(16, 32);
    sgemm_bias<<<gg, 256, 0, stream>>>(X0, wih0f, b0f, PRE,         4096, 2048, 300);
    sgemm_bias<<<gg, 256, 0, stream>>>(X0, wih0b, b0b, PRE + PREST, 4096, 2048, 300);
    lstm_rec<<<2 * RK, RTH, 0, stream>>>(PRE, PRE + PREST, whh0f, whh0b, X1, HBUF, CNT);

    sgemm_bias<<<gg, 256, 0, stream>>>(X1, wih1f, b1f, PRE,         4096, 2048, 1024);
    sgemm_bias<<<gg, 256, 0, stream>>>(X1, wih1b, b1b, PRE + PREST, 4096, 2048, 1024);
    lstm_rec<<<2 * RK, RTH, 0, stream>>>(PRE, PRE + PREST, whh1f, whh1b, X2, HBUF + 1024, CNT + 8192);

    emissions_kernel<<<4096, 256, 0, stream>>>(X2, wout, bout, EMb);
    num_kernel<<<1, 256, 0, stream>>>(EMb, tags, sttr, entr, trans, NUMv);
    crf_stage1<<<256, 576, 0, stream>>>(EMb, trans, CH);
    crf_combine<<<16, 576, 0, stream>>>(CH, P2, 16);
    crf_final<<<1, 576, 0, stream>>>(P2, EMb, sttr, entr, NUMv, (float*)d_out);
}

// Round 2
// 25368.451 us; speedup vs baseline: 1.4310x; 1.4310x over previous
//
#include <hip/hip_runtime.h>

#define RK 16          // workgroups per LSTM direction
#define RTH 512        // threads per recurrence WG
#define SEQ 4096
#define HID 512
#define NT 24

__device__ __forceinline__ float sigf(float x) { return 1.f / (1.f + __expf(-x)); }
__device__ __forceinline__ float tanhfast(float x) {
    const float e = __expf(2.f * x);
    return 1.f - 2.f / (e + 1.f);
}

// ---------------- init: zero sync flags + embedding gather ----------------
__global__ __launch_bounds__(64)
void init_gather(const float* __restrict__ emb, const int* __restrict__ sent,
                 float* __restrict__ X0, unsigned int* __restrict__ cnt)
{
    const int b = blockIdx.x, tid = threadIdx.x;
    if (b < 256) cnt[b * 64 + tid] = 0u;           // 16384 flag words
    const size_t row = (size_t)sent[b] * 300;
    for (int e = tid; e < 300; e += 64)
        X0[(size_t)b * 300 + e] = emb[row + e];
}

// ---------------- fp32 GEMM: C[M,N] = A[M,K] @ W[N,K]^T + bias[N] ----------------
__global__ __launch_bounds__(256)
void sgemm_bias(const float* __restrict__ A, const float* __restrict__ W,
                const float* __restrict__ bias, float* __restrict__ C,
                int M, int N, int K)
{
    __shared__ float As[8][128];
    __shared__ float Ws[8][128];
    const int tid = threadIdx.x;
    const int m0 = blockIdx.y * 128, n0 = blockIdx.x * 128;
    const int tx = tid & 15, ty = tid >> 4;
    const int lr = tid >> 1, lk = (tid & 1) * 4;
    float acc[8][8] = {};
    for (int k0 = 0; k0 < K; k0 += 8) {
#pragma unroll
        for (int u = 0; u < 4; ++u) {
            const int k = k0 + lk + u;
            As[lk + u][lr] = (k < K) ? A[(size_t)(m0 + lr) * K + k] : 0.f;
            Ws[lk + u][lr] = (k < K) ? W[(size_t)(n0 + lr) * K + k] : 0.f;
        }
        __syncthreads();
#pragma unroll
        for (int kk = 0; kk < 8; ++kk) {
            float a[8], b[8];
#pragma unroll
            for (int i = 0; i < 8; ++i) a[i] = As[kk][ty * 8 + i];
#pragma unroll
            for (int i = 0; i < 8; ++i) b[i] = Ws[kk][tx * 8 + i];
#pragma unroll
            for (int i = 0; i < 8; ++i)
#pragma unroll
                for (int j = 0; j < 8; ++j) acc[i][j] += a[i] * b[j];
        }
        __syncthreads();
    }
#pragma unroll
    for (int i = 0; i < 8; ++i) {
        const int m = m0 + ty * 8 + i;
#pragma unroll
        for (int j = 0; j < 8; ++j) {
            const int n = n0 + tx * 8 + j;
            C[(size_t)m * N + n] = acc[i][j] + bias[n];
        }
    }
}

// ---------------- LSTM recurrence: both directions of one layer ----------------
// grid = 32 WGs (16 per direction), 512 threads each. Weight quarter-rows in
// registers (NO spill: launch_bounds(512,1) -> up to 512 VGPR cap, need ~170).
// Cross-WG exchange: per-slot epoch flag, release-store by tid0 (all h stores
// are wave 0 -> wave-level vmcnt(0) covers them), relaxed agent polls/loads.
__global__ __launch_bounds__(RTH, 1)
void lstm_rec(const float* __restrict__ pre_f, const float* __restrict__ pre_b,
              const float* __restrict__ whh_f, const float* __restrict__ whh_b,
              float* __restrict__ out,           // (4096 x 1024): fwd [0,512), bwd [512,1024)
              float* __restrict__ hbuf,          // 2 x 512
              unsigned int* __restrict__ flags)  // 2 x RK, pre-zeroed
{
    const int g = blockIdx.x;
    const int dir = g / RK, slot = g % RK;
    const float* pre = dir ? pre_b : pre_f;
    const float* whh = dir ? whh_b : whh_f;
    float* hg = hbuf + dir * HID;
    unsigned int* flg = flags + dir * RK;

    const int tid = threadIdx.x;
    // wave-uniform quarter index q; row r in [0,128)
    const int q = (tid >> 6) & 3;
    const int r = (tid & 63) | ((tid >> 8) << 6);
    const int gate = r >> 5, jl = r & 31;
    const int grow = gate * HID + slot * 32 + jl;  // row of W_hh / pre, in [0,2048)

    // preload 128 weights (quarter of the 512-wide row) into registers
    float w[128];
    {
        const float4* wp = (const float4*)(whh + (size_t)grow * HID + q * 128);
#pragma unroll
        for (int i = 0; i < 32; ++i) {
            const float4 v = wp[i];
            w[4 * i + 0] = v.x; w[4 * i + 1] = v.y; w[4 * i + 2] = v.z; w[4 * i + 3] = v.w;
        }
    }

    __shared__ float h_sm[HID];
    __shared__ float zpart[128][5];   // +1 pad
    __shared__ float zrow[128];
    float c_state = 0.f;

    h_sm[tid] = 0.f;
    __syncthreads();

    float pre_v = 0.f;
    if (q == 0) pre_v = pre[(size_t)(dir ? (SEQ - 1) : 0) * 2048 + grow];

    for (int t = 0; t < SEQ; ++t) {
        const int tt = dir ? (SEQ - 1 - t) : t;

        // partial dot: w[0:128] . h_sm[q*128 : q*128+128]  (wave-uniform LDS broadcast)
        float acc = 0.f;
        const float4* hp = (const float4*)(h_sm + q * 128);
#pragma unroll
        for (int i = 0; i < 32; ++i) {
            const float4 hv = hp[i];
            acc += w[4 * i + 0] * hv.x + w[4 * i + 1] * hv.y
                 + w[4 * i + 2] * hv.z + w[4 * i + 3] * hv.w;
        }
        zpart[r][q] = acc;

        // prefetch next step's pre (hidden under the whole exchange)
        float pre_next = 0.f;
        if (q == 0 && t + 1 < SEQ) {
            const int tn = dir ? (SEQ - 2 - t) : (t + 1);
            pre_next = pre[(size_t)tn * 2048 + grow];
        }
        __syncthreads();

        if (q == 0)
            zrow[r] = zpart[r][0] + zpart[r][1] + zpart[r][2] + zpart[r][3] + pre_v;
        __syncthreads();

        if (tid < 32) {
            const int j = tid;
            const float zi = zrow[j], zf = zrow[32 + j], zg = zrow[64 + j], zo = zrow[96 + j];
            const float ig = sigf(zi), fg = sigf(zf), og = sigf(zo);
            c_state = fg * c_state + ig * tanhfast(zg);
            const float h = og * tanhfast(c_state);
            out[(size_t)tt * 1024 + dir * HID + slot * 32 + j] = h;
            __hip_atomic_store(hg + slot * 32 + j, h, __ATOMIC_RELAXED, __HIP_MEMORY_SCOPE_AGENT);
        }

        if (t + 1 < SEQ) {
            // release store: wave-level s_waitcnt vmcnt(0) orders wave 0's h stores
            if (tid == 0)
                __hip_atomic_store(&flg[slot], (unsigned)(t + 1),
                                   __ATOMIC_RELEASE, __HIP_MEMORY_SCOPE_AGENT);
            if (tid < RK)
                while (__hip_atomic_load(&flg[tid], __ATOMIC_RELAXED,
                                         __HIP_MEMORY_SCOPE_AGENT) < (unsigned)(t + 1)) {}
            __syncthreads();
            h_sm[tid] = __hip_atomic_load(hg + tid, __ATOMIC_RELAXED,
                                          __HIP_MEMORY_SCOPE_AGENT);
            __syncthreads();
        }
        pre_v = pre_next;
    }
}

// ---------------- emissions: EM[4096,24] = X2[4096,1024] @ Wo[24,1024]^T + bo ----------------
__global__ __launch_bounds__(256)
void emissions_kernel(const float* __restrict__ X, const float* __restrict__ Wo,
                      const float* __restrict__ bo, float* __restrict__ EM)
{
    __shared__ float xs[1024];
    __shared__ float red[NT][9];
    const int t = blockIdx.x, tid = threadIdx.x;
    for (int i = tid; i < 1024; i += 256) xs[i] = X[(size_t)t * 1024 + i];
    __syncthreads();
    const int col = tid >> 3, s = tid & 7;
    if (col < NT) {
        float acc = 0.f;
        const float* wr = Wo + (size_t)col * 1024 + s * 128;
        const float* xp = xs + s * 128;
#pragma unroll 8
        for (int i = 0; i < 128; ++i) acc += wr[i] * xp[i];
        red[col][s] = acc;
    }
    __syncthreads();
    if (tid < NT) {
        float rsum = 0.f;
#pragma unroll
        for (int s2 = 0; s2 < 8; ++s2) rsum += red[tid][s2];
        EM[t * NT + tid] = rsum + bo[tid];
    }
}

// ---------------- numerator ----------------
__global__ __launch_bounds__(256)
void num_kernel(const float* __restrict__ EM, const int* __restrict__ tags,
                const float* __restrict__ stt, const float* __restrict__ ent,
                const float* __restrict__ tr, float* __restrict__ numout)
{
    __shared__ float red[256];
    const int tid = threadIdx.x;
    float acc = 0.f;
    for (int t = tid; t < SEQ; t += 256) {
        const int tg = tags[t];
        acc += EM[t * NT + tg];
        if (t < SEQ - 1) acc += tr[tg * NT + tags[t + 1]];
    }
    red[tid] = acc; __syncthreads();
    for (int s = 128; s > 0; s >>= 1) { if (tid < s) red[tid] += red[tid + s]; __syncthreads(); }
    if (tid == 0) numout[0] = red[0] + stt[tags[0]] + ent[tags[SEQ - 1]];
}

// ---------------- CRF stage 1: chunk products of M_t (t=1..4095), 16 per chunk ----------------
__global__ __launch_bounds__(576)
void crf_stage1(const float* __restrict__ EM, const float* __restrict__ trans,
                float* __restrict__ CH)
{
    __shared__ float tr[NT][NT];
    __shared__ float cur[2][NT][NT + 1];
    const int tid = threadIdx.x;
    const int i = tid / NT, j = tid % NT;
    const int c = blockIdx.x;
    const int t0 = 1 + c * 16;
    const int cm = min(16, SEQ - t0);
    const float trv = trans[i * NT + j];
    tr[i][j] = trv;
    cur[0][i][j] = trv + EM[t0 * NT + j];
    __syncthreads();
    int pp = 0;
    for (int s = 1; s < cm; ++s) {
        const float e = EM[(t0 + s) * NT + j];
        float m = -1e30f;
#pragma unroll
        for (int k = 0; k < NT; ++k) m = fmaxf(m, cur[pp][i][k] + tr[k][j]);
        float sum = 0.f;
#pragma unroll
        for (int k = 0; k < NT; ++k) sum += __expf(cur[pp][i][k] + tr[k][j] - m);
        cur[1 - pp][i][j] = m + __logf(sum) + e;
        pp = 1 - pp;
        __syncthreads();
    }
    CH[(size_t)c * 576 + i * NT + j] = cur[pp][i][j];
}

// ---------------- CRF combine: block c folds IN[c*per .. c*per+per) in order ----------------
__global__ __launch_bounds__(576)
void crf_combine(const float* __restrict__ IN, float* __restrict__ OUT, int per)
{
    __shared__ float cur[2][NT][NT + 1];
    const int tid = threadIdx.x;
    const int i = tid / NT, j = tid % NT;
    const int c = blockIdx.x;
    const float* base = IN + (size_t)c * per * 576;
    cur[0][i][j] = base[i * NT + j];
    __syncthreads();
    int pp = 0;
    for (int s = 1; s < per; ++s) {
        const float* B = base + (size_t)s * 576;
        float m = -1e30f;
#pragma unroll
        for (int k = 0; k < NT; ++k) m = fmaxf(m, cur[pp][i][k] + B[k * NT + j]);
        float sum = 0.f;
#pragma unroll
        for (int k = 0; k < NT; ++k) sum += __expf(cur[pp][i][k] + B[k * NT + j] - m);
        cur[1 - pp][i][j] = m + __logf(sum);
        pp = 1 - pp;
        __syncthreads();
    }
    OUT[(size_t)c * 576 + i * NT + j] = cur[pp][i][j];
}

// ---------------- CRF final: fold 16 partials, den, out = den - num ----------------
__global__ __launch_bounds__(576)
void crf_final(const float* __restrict__ P2, const float* __restrict__ EM,
               const float* __restrict__ stt, const float* __restrict__ ent,
               const float* __restrict__ numptr, float* __restrict__ outp)
{
    __shared__ float cur[2][NT][NT + 1];
    __shared__ float red[1024];
    const int tid = threadIdx.x;
    const int i = tid / NT, j = tid % NT;
    cur[0][i][j] = P2[i * NT + j];
    __syncthreads();
    int pp = 0;
    for (int s = 1; s < 16; ++s) {
        const float* B = P2 + (size_t)s * 576;
        float m = -1e30f;
#pragma unroll
        for (int k = 0; k < NT; ++k) m = fmaxf(m, cur[pp][i][k] + B[k * NT + j]);
        float sum = 0.f;
#pragma unroll
        for (int k = 0; k < NT; ++k) sum += __expf(cur[pp][i][k] + B[k * NT + j] - m);
        cur[1 - pp][i][j] = m + __logf(sum);
        pp = 1 - pp;
        __syncthreads();
    }
    const float v = stt[i] + EM[i] + cur[pp][i][j] + ent[j];
    red[tid] = v;
    for (int t2 = tid + 576; t2 < 1024; t2 += 576) red[t2] = -1e30f;
    __syncthreads();
    for (int s2 = 512; s2 > 0; s2 >>= 1) {
        if (tid < s2) red[tid] = fmaxf(red[tid], red[tid + s2]);
        __syncthreads();
    }
    const float m = red[0];
    __syncthreads();
    red[tid] = __expf(v - m);
    for (int t2 = tid + 576; t2 < 1024; t2 += 576) red[t2] = 0.f;
    __syncthreads();
    for (int s2 = 512; s2 > 0; s2 >>= 1) {
        if (tid < s2) red[tid] += red[tid + s2];
        __syncthreads();
    }
    if (tid == 0) outp[0] = m + __logf(red[0]) - numptr[0];
}

// ---------------- launcher ----------------
extern "C" void kernel_launch(void* const* d_in, const int* in_sizes, int n_in,
                              void* d_out, int out_size, void* d_ws, size_t ws_size,
                              hipStream_t stream)
{
    const float* emb    = (const float*)d_in[0];
    const float* wih0f  = (const float*)d_in[1];
    const float* whh0f  = (const float*)d_in[2];
    const float* b0f    = (const float*)d_in[3];
    const float* wih0b  = (const float*)d_in[4];
    const float* whh0b  = (const float*)d_in[5];
    const float* b0b    = (const float*)d_in[6];
    const float* wih1f  = (const float*)d_in[7];
    const float* whh1f  = (const float*)d_in[8];
    const float* b1f    = (const float*)d_in[9];
    const float* wih1b  = (const float*)d_in[10];
    const float* whh1b  = (const float*)d_in[11];
    const float* b1b    = (const float*)d_in[12];
    const float* wout   = (const float*)d_in[13];
    const float* bout   = (const float*)d_in[14];
    const float* sttr   = (const float*)d_in[15];
    const float* entr   = (const float*)d_in[16];
    const float* trans  = (const float*)d_in[17];
    const int*   sent   = (const int*)d_in[18];
    const int*   tags   = (const int*)d_in[19];

    float* ws = (float*)d_ws;
    float* X0   = ws;                          // 4096*300
    float* PRE  = X0 + 1228800;                // 2 * 4096*2048
    float* X1   = PRE + 16777216;              // 4096*1024
    float* X2   = X1 + 4194304;                // 4096*1024
    float* EMb  = X2 + 4194304;                // 4096*24
    float* CH   = EMb + 98304;                 // 256*576
    float* P2   = CH + 147456;                 // 16*576
    float* NUMv = P2 + 9216;                   // 1 (padded 64)
    float* HBUF = NUMv + 64;                   // 4*512
    unsigned int* CNT = (unsigned int*)(HBUF + 2048); // 16384 words

    const int PREST = 8388608; // per-direction stride in PRE

    init_gather<<<4096, 64, 0, stream>>>(emb, sent, X0, CNT);

    dim3 gg(16, 32);
    sgemm_bias<<<gg, 256, 0, stream>>>(X0, wih0f, b0f, PRE,         4096, 2048, 300);
    sgemm_bias<<<gg, 256, 0, stream>>>(X0, wih0b, b0b, PRE + PREST, 4096, 2048, 300);
    lstm_rec<<<2 * RK, RTH, 0, stream>>>(PRE, PRE + PREST, whh0f, whh0b, X1, HBUF, CNT);

    sgemm_bias<<<gg, 256, 0, stream>>>(X1, wih1f, b1f, PRE,         4096, 2048, 1024);
    sgemm_bias<<<gg, 256, 0, stream>>>(X1, wih1b, b1b, PRE + PREST, 4096, 2048, 1024);
    lstm_rec<<<2 * RK, RTH, 0, stream>>>(PRE, PRE + PREST, whh1f, whh1b, X2, HBUF + 1024, CNT + 8192);

    emissions_kernel<<<4096, 256, 0, stream>>>(X2, wout, bout, EMb);
    num_kernel<<<1, 256, 0, stream>>>(EMb, tags, sttr, entr, trans, NUMv);
    crf_stage1<<<256, 576, 0, stream>>>(EMb, trans, CH);
    crf_combine<<<16, 576, 0, stream>>>(CH, P2, 16);
    crf_final<<<1, 576, 0, stream>>>(P2, EMb, sttr, entr, NUMv, (float*)d_out);
}

// Round 4
// 24014.874 us; speedup vs baseline: 1.5117x; 1.0564x over previous
//
#include <hip/hip_runtime.h>

#define RK 32          // workgroups per LSTM direction
#define RTH 1024       // threads per recurrence WG
#define UPS 16         // hidden units per slot (512/RK)
#define SEQ 4096
#define HID 512
#define NT 24

__device__ __forceinline__ float sigf(float x) { return 1.f / (1.f + __expf(-x)); }
__device__ __forceinline__ float tanhfast(float x) {
    const float e = __expf(2.f * x);
    return 1.f - 2.f / (e + 1.f);
}

// ---------------- init: zero sync flags + embedding gather ----------------
__global__ __launch_bounds__(64)
void init_gather(const float* __restrict__ emb, const int* __restrict__ sent,
                 float* __restrict__ X0, unsigned int* __restrict__ flags)
{
    const int b = blockIdx.x, tid = threadIdx.x;
    if (b < 2) flags[b * 64 + tid] = 0u;           // 128 flag words
    const size_t row = (size_t)sent[b] * 300;
    for (int e = tid; e < 300; e += 64)
        X0[(size_t)b * 300 + e] = emb[row + e];
}

// ---------------- fp32 GEMM: C[M,N] = A[M,K] @ W[N,K]^T + bias[N] ----------------
__global__ __launch_bounds__(256)
void sgemm_bias(const float* __restrict__ A, const float* __restrict__ W,
                const float* __restrict__ bias, float* __restrict__ C,
                int M, int N, int K)
{
    __shared__ float As[8][128];
    __shared__ float Ws[8][128];
    const int tid = threadIdx.x;
    const int m0 = blockIdx.y * 128, n0 = blockIdx.x * 128;
    const int tx = tid & 15, ty = tid >> 4;
    const int lr = tid >> 1, lk = (tid & 1) * 4;
    float acc[8][8] = {};
    for (int k0 = 0; k0 < K; k0 += 8) {
#pragma unroll
        for (int u = 0; u < 4; ++u) {
            const int k = k0 + lk + u;
            As[lk + u][lr] = (k < K) ? A[(size_t)(m0 + lr) * K + k] : 0.f;
            Ws[lk + u][lr] = (k < K) ? W[(size_t)(n0 + lr) * K + k] : 0.f;
        }
        __syncthreads();
#pragma unroll
        for (int kk = 0; kk < 8; ++kk) {
            float a[8], b[8];
#pragma unroll
            for (int i = 0; i < 8; ++i) a[i] = As[kk][ty * 8 + i];
#pragma unroll
            for (int i = 0; i < 8; ++i) b[i] = Ws[kk][tx * 8 + i];
#pragma unroll
            for (int i = 0; i < 8; ++i)
#pragma unroll
                for (int j = 0; j < 8; ++j) acc[i][j] += a[i] * b[j];
        }
        __syncthreads();
    }
#pragma unroll
    for (int i = 0; i < 8; ++i) {
        const int m = m0 + ty * 8 + i;
#pragma unroll
        for (int j = 0; j < 8; ++j) {
            const int n = n0 + tx * 8 + j;
            C[(size_t)m * N + n] = acc[i][j] + bias[n];
        }
    }
}

// ---------------- LSTM recurrence, v4 ----------------
// v3 compute layout (32 weights/thread in VGPRs, 2*RK=64 WGs x 1024 thr) +
// v2's HW-proven exchange (wave-0 h stores -> tid0 RELEASE flag -> poll ->
// h reload). Thread (rsub=tid&31, seg=tid>>5) owns local rows {rsub,rsub+32}
// of 64 x cols [seg*16, seg*16+16).
__global__ __launch_bounds__(RTH, 2)
void lstm_rec(const float* __restrict__ pre_f, const float* __restrict__ pre_b,
              const float* __restrict__ whh_f, const float* __restrict__ whh_b,
              float* __restrict__ out,           // (4096 x 1024): fwd [0,512), bwd [512,1024)
              float* __restrict__ hbuf,          // 2 x 512 (this layer's region)
              unsigned int* __restrict__ flags)  // 2 x RK (this layer's region), pre-zeroed
{
    const int g = blockIdx.x;
    const int dir = g / RK, slot = g % RK;
    const float* pre = dir ? pre_b : pre_f;
    const float* whh = dir ? whh_b : whh_f;
    float* hg = hbuf + dir * HID;
    unsigned int* flg = flags + dir * RK;

    const int tid = threadIdx.x;
    const int seg = tid >> 5;        // 0..31 (16-col segment)
    const int rsub = tid & 31;       // 0..31

    // local row r = k*16 + j (k=gate 0..3, j=unit 0..15); global z-row =
    // gate*512 + slot*16 + j. Thread owns local rows rsub (gates 0/1) and
    // rsub+32 (gates 2/3).
    const int k0g = rsub >> 4, j0 = rsub & 15;
    const int grow0 = k0g * HID + slot * UPS + j0;
    const int grow1 = (k0g + 2) * HID + slot * UPS + j0;

    float4 w0[4], w1[4];
    {
        const float4* p0 = (const float4*)(whh + (size_t)grow0 * HID + seg * 16);
        const float4* p1 = (const float4*)(whh + (size_t)grow1 * HID + seg * 16);
#pragma unroll
        for (int c = 0; c < 4; ++c) { w0[c] = p0[c]; w1[c] = p1[c]; }
    }

    // reduction thread (tid<64) row mapping
    const int rr = tid & 63;
    const int growr = (rr >> 4) * HID + slot * UPS + (rr & 15);

    __shared__ float h_sm[HID];
    __shared__ float zz[64][33];
    __shared__ float zrow[64];
    float c_state = 0.f;

    if (tid < HID) h_sm[tid] = 0.f;
    __syncthreads();

    float pre_v = 0.f;
    if (tid < 64) pre_v = pre[(size_t)(dir ? (SEQ - 1) : 0) * 2048 + growr];

    for (int t = 0; t < SEQ; ++t) {
        const int tt = dir ? (SEQ - 1 - t) : t;
        const bool not_last = (t + 1 < SEQ);

        // dot: 2 rows x 16 cols against h_sm[seg*16 ..]
        const float4* hp = (const float4*)(h_sm + seg * 16);
        const float4 h0 = hp[0], h1 = hp[1], h2 = hp[2], h3 = hp[3];
        float a0, a1;
        {
            a0  = w0[0].x*h0.x + w0[0].y*h0.y + w0[0].z*h0.z + w0[0].w*h0.w;
            a0 += w0[1].x*h1.x + w0[1].y*h1.y + w0[1].z*h1.z + w0[1].w*h1.w;
            a0 += w0[2].x*h2.x + w0[2].y*h2.y + w0[2].z*h2.z + w0[2].w*h2.w;
            a0 += w0[3].x*h3.x + w0[3].y*h3.y + w0[3].z*h3.z + w0[3].w*h3.w;
            a1  = w1[0].x*h0.x + w1[0].y*h0.y + w1[0].z*h0.z + w1[0].w*h0.w;
            a1 += w1[1].x*h1.x + w1[1].y*h1.y + w1[1].z*h1.z + w1[1].w*h1.w;
            a1 += w1[2].x*h2.x + w1[2].y*h2.y + w1[2].z*h2.z + w1[2].w*h2.w;
            a1 += w1[3].x*h3.x + w1[3].y*h3.y + w1[3].z*h3.z + w1[3].w*h3.w;
        }
        zz[rsub][seg] = a0;
        zz[rsub + 32][seg] = a1;
        __syncthreads();

        // prefetch next step's pre (completes during exchange)
        float pre_next = 0.f;
        if (tid < 64 && not_last) {
            const int tn = dir ? (SEQ - 2 - t) : (t + 1);
            pre_next = pre[(size_t)tn * 2048 + growr];
        }

        if (tid < 64) {
            float s = pre_v;
#pragma unroll
            for (int c = 0; c < 32; ++c) s += zz[tid][c];
            zrow[tid] = s;
        }
        __syncthreads();

        if (tid < UPS) {
            const int j = tid;
            const float zi = zrow[j], zf = zrow[UPS + j],
                        zg = zrow[2 * UPS + j], zo = zrow[3 * UPS + j];
            const float ig = sigf(zi), fg = sigf(zf), og = sigf(zo);
            c_state = fg * c_state + ig * tanhfast(zg);
            const float h = og * tanhfast(c_state);
            out[(size_t)tt * 1024 + dir * HID + slot * UPS + j] = h;
            if (not_last)
                __hip_atomic_store(hg + slot * UPS + j, h,
                                   __ATOMIC_RELAXED, __HIP_MEMORY_SCOPE_AGENT);
        }

        if (not_last) {
            // release store from the same wave that issued the h stores:
            // s_waitcnt vmcnt(0) drains them before the flag becomes visible
            if (tid == 0)
                __hip_atomic_store(&flg[slot], (unsigned)(t + 1),
                                   __ATOMIC_RELEASE, __HIP_MEMORY_SCOPE_AGENT);
            if (tid < RK)
                while (__hip_atomic_load(&flg[tid], __ATOMIC_RELAXED,
                                         __HIP_MEMORY_SCOPE_AGENT) < (unsigned)(t + 1)) {}
            __syncthreads();
            if (tid < HID)
                h_sm[tid] = __hip_atomic_load(hg + tid, __ATOMIC_RELAXED,
                                              __HIP_MEMORY_SCOPE_AGENT);
            __syncthreads();
        }
        pre_v = pre_next;
    }
}

// ---------------- emissions: EM[4096,24] = X2[4096,1024] @ Wo[24,1024]^T + bo ----------------
__global__ __launch_bounds__(256)
void emissions_kernel(const float* __restrict__ X, const float* __restrict__ Wo,
                      const float* __restrict__ bo, float* __restrict__ EM)
{
    __shared__ float xs[1024];
    __shared__ float red[NT][9];
    const int t = blockIdx.x, tid = threadIdx.x;
    for (int i = tid; i < 1024; i += 256) xs[i] = X[(size_t)t * 1024 + i];
    __syncthreads();
    const int col = tid >> 3, s = tid & 7;
    if (col < NT) {
        float acc = 0.f;
        const float* wr = Wo + (size_t)col * 1024 + s * 128;
        const float* xp = xs + s * 128;
#pragma unroll 8
        for (int i = 0; i < 128; ++i) acc += wr[i] * xp[i];
        red[col][s] = acc;
    }
    __syncthreads();
    if (tid < NT) {
        float rsum = 0.f;
#pragma unroll
        for (int s2 = 0; s2 < 8; ++s2) rsum += red[tid][s2];
        EM[t * NT + tid] = rsum + bo[tid];
    }
}

// ---------------- numerator ----------------
__global__ __launch_bounds__(256)
void num_kernel(const float* __restrict__ EM, const int* __restrict__ tags,
                const float* __restrict__ stt, const float* __restrict__ ent,
                const float* __restrict__ tr, float* __restrict__ numout)
{
    __shared__ float red[256];
    const int tid = threadIdx.x;
    float acc = 0.f;
    for (int t = tid; t < SEQ; t += 256) {
        const int tg = tags[t];
        acc += EM[t * NT + tg];
        if (t < SEQ - 1) acc += tr[tg * NT + tags[t + 1]];
    }
    red[tid] = acc; __syncthreads();
    for (int s = 128; s > 0; s >>= 1) { if (tid < s) red[tid] += red[tid + s]; __syncthreads(); }
    if (tid == 0) numout[0] = red[0] + stt[tags[0]] + ent[tags[SEQ - 1]];
}

// ---------------- CRF stage 1: chunk products of M_t (t=1..4095), 16 per chunk ----------------
__global__ __launch_bounds__(576)
void crf_stage1(const float* __restrict__ EM, const float* __restrict__ trans,
                float* __restrict__ CH)
{
    __shared__ float tr[NT][NT];
    __shared__ float cur[2][NT][NT + 1];
    const int tid = threadIdx.x;
    const int i = tid / NT, j = tid % NT;
    const int c = blockIdx.x;
    const int t0 = 1 + c * 16;
    const int cm = min(16, SEQ - t0);
    const float trv = trans[i * NT + j];
    tr[i][j] = trv;
    cur[0][i][j] = trv + EM[t0 * NT + j];
    __syncthreads();
    int pp = 0;
    for (int s = 1; s < cm; ++s) {
        const float e = EM[(t0 + s) * NT + j];
        float m = -1e30f;
#pragma unroll
        for (int k = 0; k < NT; ++k) m = fmaxf(m, cur[pp][i][k] + tr[k][j]);
        float sum = 0.f;
#pragma unroll
        for (int k = 0; k < NT; ++k) sum += __expf(cur[pp][i][k] + tr[k][j] - m);
        cur[1 - pp][i][j] = m + __logf(sum) + e;
        pp = 1 - pp;
        __syncthreads();
    }
    CH[(size_t)c * 576 + i * NT + j] = cur[pp][i][j];
}

// ---------------- CRF combine ----------------
__global__ __launch_bounds__(576)
void crf_combine(const float* __restrict__ IN, float* __restrict__ OUT, int per)
{
    __shared__ float cur[2][NT][NT + 1];
    const int tid = threadIdx.x;
    const int i = tid / NT, j = tid % NT;
    const int c = blockIdx.x;
    const float* base = IN + (size_t)c * per * 576;
    cur[0][i][j] = base[i * NT + j];
    __syncthreads();
    int pp = 0;
    for (int s = 1; s < per; ++s) {
        const float* B = base + (size_t)s * 576;
        float m = -1e30f;
#pragma unroll
        for (int k = 0; k < NT; ++k) m = fmaxf(m, cur[pp][i][k] + B[k * NT + j]);
        float sum = 0.f;
#pragma unroll
        for (int k = 0; k < NT; ++k) sum += __expf(cur[pp][i][k] + B[k * NT + j] - m);
        cur[1 - pp][i][j] = m + __logf(sum);
        pp = 1 - pp;
        __syncthreads();
    }
    OUT[(size_t)c * 576 + i * NT + j] = cur[pp][i][j];
}

// ---------------- CRF final ----------------
__global__ __launch_bounds__(576)
void crf_final(const float* __restrict__ P2, const float* __restrict__ EM,
               const float* __restrict__ stt, const float* __restrict__ ent,
               const float* __restrict__ numptr, float* __restrict__ outp)
{
    __shared__ float cur[2][NT][NT + 1];
    __shared__ float red[1024];
    const int tid = threadIdx.x;
    const int i = tid / NT, j = tid % NT;
    cur[0][i][j] = P2[i * NT + j];
    __syncthreads();
    int pp = 0;
    for (int s = 1; s < 16; ++s) {
        const float* B = P2 + (size_t)s * 576;
        float m = -1e30f;
#pragma unroll
        for (int k = 0; k < NT; ++k) m = fmaxf(m, cur[pp][i][k] + B[k * NT + j]);
        float sum = 0.f;
#pragma unroll
        for (int k = 0; k < NT; ++k) sum += __expf(cur[pp][i][k] + B[k * NT + j] - m);
        cur[1 - pp][i][j] = m + __logf(sum);
        pp = 1 - pp;
        __syncthreads();
    }
    const float v = stt[i] + EM[i] + cur[pp][i][j] + ent[j];
    red[tid] = v;
    for (int t2 = tid + 576; t2 < 1024; t2 += 576) red[t2] = -1e30f;
    __syncthreads();
    for (int s2 = 512; s2 > 0; s2 >>= 1) {
        if (tid < s2) red[tid] = fmaxf(red[tid], red[tid + s2]);
        __syncthreads();
    }
    const float m = red[0];
    __syncthreads();
    red[tid] = __expf(v - m);
    for (int t2 = tid + 576; t2 < 1024; t2 += 576) red[t2] = 0.f;
    __syncthreads();
    for (int s2 = 512; s2 > 0; s2 >>= 1) {
        if (tid < s2) red[tid] += red[tid + s2];
        __syncthreads();
    }
    if (tid == 0) outp[0] = m + __logf(red[0]) - numptr[0];
}

// ---------------- launcher ----------------
extern "C" void kernel_launch(void* const* d_in, const int* in_sizes, int n_in,
                              void* d_out, int out_size, void* d_ws, size_t ws_size,
                              hipStream_t stream)
{
    const float* emb    = (const float*)d_in[0];
    const float* wih0f  = (const float*)d_in[1];
    const float* whh0f  = (const float*)d_in[2];
    const float* b0f    = (const float*)d_in[3];
    const float* wih0b  = (const float*)d_in[4];
    const float* whh0b  = (const float*)d_in[5];
    const float* b0b    = (const float*)d_in[6];
    const float* wih1f  = (const float*)d_in[7];
    const float* whh1f  = (const float*)d_in[8];
    const float* b1f    = (const float*)d_in[9];
    const float* wih1b  = (const float*)d_in[10];
    const float* whh1b  = (const float*)d_in[11];
    const float* b1b    = (const float*)d_in[12];
    const float* wout   = (const float*)d_in[13];
    const float* bout   = (const float*)d_in[14];
    const float* sttr   = (const float*)d_in[15];
    const float* entr   = (const float*)d_in[16];
    const float* trans  = (const float*)d_in[17];
    const int*   sent   = (const int*)d_in[18];
    const int*   tags   = (const int*)d_in[19];

    float* ws = (float*)d_ws;
    float* X0   = ws;                          // 4096*300
    float* PRE  = X0 + 1228800;                // 2 * 4096*2048
    float* X1   = PRE + 16777216;              // 4096*1024
    float* X2   = X1 + 4194304;                // 4096*1024
    float* EMb  = X2 + 4194304;                // 4096*24
    float* CH   = EMb + 98304;                 // 256*576
    float* P2   = CH + 147456;                 // 16*576
    float* NUMv = P2 + 9216;                   // 1 (padded 64)
    float* HBUF = NUMv + 64;                   // 2 layers x 1024
    unsigned int* CNT = (unsigned int*)(HBUF + 2048); // 128 flag words

    const int PREST = 8388608; // per-direction stride in PRE

    init_gather<<<4096, 64, 0, stream>>>(emb, sent, X0, CNT);

    dim3 gg(16, 32);
    sgemm_bias<<<gg, 256, 0, stream>>>(X0, wih0f, b0f, PRE,         4096, 2048, 300);
    sgemm_bias<<<gg, 256, 0, stream>>>(X0, wih0b, b0b, PRE + PREST, 4096, 2048, 300);
    lstm_rec<<<2 * RK, RTH, 0, stream>>>(PRE, PRE + PREST, whh0f, whh0b, X1, HBUF, CNT);

    sgemm_bias<<<gg, 256, 0, stream>>>(X1, wih1f, b1f, PRE,         4096, 2048, 1024);
    sgemm_bias<<<gg, 256, 0, stream>>>(X1, wih1b, b1b, PRE + PREST, 4096, 2048, 1024);
    lstm_rec<<<2 * RK, RTH, 0, stream>>>(PRE, PRE + PREST, whh1f, whh1b, X2, HBUF + 1024, CNT + 64);

    emissions_kernel<<<4096, 256, 0, stream>>>(X2, wout, bout, EMb);
    num_kernel<<<1, 256, 0, stream>>>(EMb, tags, sttr, entr, trans, NUMv);
    crf_stage1<<<256, 576, 0, stream>>>(EMb, trans, CH);
    crf_combine<<<16, 576, 0, stream>>>(CH, P2, 16);
    crf_final<<<1, 576, 0, stream>>>(P2, EMb, sttr, entr, NUMv, (float*)d_out);
}

// Round 5
// 16592.323 us; speedup vs baseline: 2.1880x; 1.4473x over previous
//
#include <hip/hip_runtime.h>

#define RK 32          // workgroups per LSTM direction
#define RTH 1024       // threads per recurrence WG
#define UPS 16         // hidden units per slot (512/RK)
#define SEQ 4096
#define HID 512
#define NT 24

__device__ __forceinline__ float sigf(float x) { return 1.f / (1.f + __expf(-x)); }
__device__ __forceinline__ float tanhfast(float x) {
    const float e = __expf(2.f * x);
    return 1.f - 2.f / (e + 1.f);
}

// ---------------- init: embedding gather ----------------
__global__ __launch_bounds__(64)
void init_gather(const float* __restrict__ emb, const int* __restrict__ sent,
                 float* __restrict__ X0)
{
    const int b = blockIdx.x, tid = threadIdx.x;
    const size_t row = (size_t)sent[b] * 300;
    for (int e = tid; e < 300; e += 64)
        X0[(size_t)b * 300 + e] = emb[row + e];
}

// ---------------- fp32 GEMM: C[M,N] = A[M,K] @ W[N,K]^T + bias[N] ----------------
__global__ __launch_bounds__(256)
void sgemm_bias(const float* __restrict__ A, const float* __restrict__ W,
                const float* __restrict__ bias, float* __restrict__ C,
                int M, int N, int K)
{
    __shared__ float As[8][128];
    __shared__ float Ws[8][128];
    const int tid = threadIdx.x;
    const int m0 = blockIdx.y * 128, n0 = blockIdx.x * 128;
    const int tx = tid & 15, ty = tid >> 4;
    const int lr = tid >> 1, lk = (tid & 1) * 4;
    float acc[8][8] = {};
    for (int k0 = 0; k0 < K; k0 += 8) {
#pragma unroll
        for (int u = 0; u < 4; ++u) {
            const int k = k0 + lk + u;
            As[lk + u][lr] = (k < K) ? A[(size_t)(m0 + lr) * K + k] : 0.f;
            Ws[lk + u][lr] = (k < K) ? W[(size_t)(n0 + lr) * K + k] : 0.f;
        }
        __syncthreads();
#pragma unroll
        for (int kk = 0; kk < 8; ++kk) {
            float a[8], b[8];
#pragma unroll
            for (int i = 0; i < 8; ++i) a[i] = As[kk][ty * 8 + i];
#pragma unroll
            for (int i = 0; i < 8; ++i) b[i] = Ws[kk][tx * 8 + i];
#pragma unroll
            for (int i = 0; i < 8; ++i)
#pragma unroll
                for (int j = 0; j < 8; ++j) acc[i][j] += a[i] * b[j];
        }
        __syncthreads();
    }
#pragma unroll
    for (int i = 0; i < 8; ++i) {
        const int m = m0 + ty * 8 + i;
#pragma unroll
        for (int j = 0; j < 8; ++j) {
            const int n = n0 + tx * 8 + j;
            C[(size_t)m * N + n] = acc[i][j] + bias[n];
        }
    }
}

// ---------------- LSTM recurrence, v5 ----------------
// 2*RK=64 WGs x 1024 thr. dir = blockIdx&1 (XCD parity grouping).
// Weights pinned in VGPRs via asm. Exchange: DOUBLE-BUFFERED (by t&1)
// self-validating h+offset stores; consumers poll the data directly.
// Skew between WGs provably <=1 step => no lap race, no flags, no fences.
__global__ __launch_bounds__(RTH, 1)
void lstm_rec(const float* __restrict__ pre_f, const float* __restrict__ pre_b,
              const float* __restrict__ whh_f, const float* __restrict__ whh_b,
              float* __restrict__ out,           // (4096 x 1024): fwd [0,512), bwd [512,1024)
              float* __restrict__ hbuf)          // this layer: 2 dirs x 2 bufs x 512
{
    const int g = blockIdx.x;
    const int dir = g & 1, slot = g >> 1;
    const float* pre = dir ? pre_b : pre_f;
    const float* whh = dir ? whh_b : whh_f;
    float* hb0 = hbuf + dir * 2 * HID;     // + (t&1)*HID selects the buffer

    const int tid = threadIdx.x;
    const int seg = tid >> 5;        // 0..31 (16-col segment)
    const int rsub = tid & 31;       // 0..31

    // local row r = k*16 + j (k=gate, j=unit); global z-row = gate*512 + slot*16 + j
    const int k0g = rsub >> 4, j0 = rsub & 15;
    const int grow0 = k0g * HID + slot * UPS + j0;
    const int grow1 = (k0g + 2) * HID + slot * UPS + j0;

    float4 w0[4], w1[4];
    {
        const float4* p0 = (const float4*)(whh + (size_t)grow0 * HID + seg * 16);
        const float4* p1 = (const float4*)(whh + (size_t)grow1 * HID + seg * 16);
#pragma unroll
        for (int c = 0; c < 4; ++c) { w0[c] = p0[c]; w1[c] = p1[c]; }
    }
    // pin all 32 weight floats in VGPRs (prevents the compiler from sinking
    // the loads into the loop, which it did in v4: VGPR_Count was 36)
    asm volatile("" : "+v"(w0[0].x), "+v"(w0[0].y), "+v"(w0[0].z), "+v"(w0[0].w),
                       "+v"(w0[1].x), "+v"(w0[1].y), "+v"(w0[1].z), "+v"(w0[1].w),
                       "+v"(w0[2].x), "+v"(w0[2].y), "+v"(w0[2].z), "+v"(w0[2].w),
                       "+v"(w0[3].x), "+v"(w0[3].y), "+v"(w0[3].z), "+v"(w0[3].w));
    asm volatile("" : "+v"(w1[0].x), "+v"(w1[0].y), "+v"(w1[0].z), "+v"(w1[0].w),
                       "+v"(w1[1].x), "+v"(w1[1].y), "+v"(w1[1].z), "+v"(w1[1].w),
                       "+v"(w1[2].x), "+v"(w1[2].y), "+v"(w1[2].z), "+v"(w1[2].w),
                       "+v"(w1[3].x), "+v"(w1[3].y), "+v"(w1[3].z), "+v"(w1[3].w));

    // reducer-lane (tid<64) row mapping
    const int rr = tid & 63;
    const int growr = (rr >> 4) * HID + slot * UPS + (rr & 15);

    __shared__ float h_sm[HID];
    __shared__ float zz[64][33];
    float c_state = 0.f;

    if (tid < HID) h_sm[tid] = 0.f;
    __syncthreads();

    float pre_v = 0.f;
    if (tid < 64) pre_v = pre[(size_t)(dir ? (SEQ - 1) : 0) * 2048 + growr];

    for (int t = 0; t < SEQ; ++t) {
        const int tt = dir ? (SEQ - 1 - t) : t;
        const bool not_last = (t + 1 < SEQ);

        // dot: 2 local rows x 16 cols against h_sm[seg*16 ..]
        const float4* hp = (const float4*)(h_sm + seg * 16);
        const float4 h0 = hp[0], h1 = hp[1], h2 = hp[2], h3 = hp[3];
        float a0, a1;
        {
            a0  = w0[0].x*h0.x + w0[0].y*h0.y + w0[0].z*h0.z + w0[0].w*h0.w;
            a0 += w0[1].x*h1.x + w0[1].y*h1.y + w0[1].z*h1.z + w0[1].w*h1.w;
            a0 += w0[2].x*h2.x + w0[2].y*h2.y + w0[2].z*h2.z + w0[2].w*h2.w;
            a0 += w0[3].x*h3.x + w0[3].y*h3.y + w0[3].z*h3.z + w0[3].w*h3.w;
            a1  = w1[0].x*h0.x + w1[0].y*h0.y + w1[0].z*h0.z + w1[0].w*h0.w;
            a1 += w1[1].x*h1.x + w1[1].y*h1.y + w1[1].z*h1.z + w1[1].w*h1.w;
            a1 += w1[2].x*h2.x + w1[2].y*h2.y + w1[2].z*h2.z + w1[2].w*h2.w;
            a1 += w1[3].x*h3.x + w1[3].y*h3.y + w1[3].z*h3.z + w1[3].w*h3.w;
        }
        zz[rsub][seg] = a0;
        zz[rsub + 32][seg] = a1;
        __syncthreads();

        // prefetch next step's pre (latency hidden under the exchange;
        // no release anywhere, so nothing force-drains this early)
        float pre_next = 0.f;
        if (tid < 64 && not_last) {
            const int tn = dir ? (SEQ - 2 - t) : (t + 1);
            pre_next = pre[(size_t)tn * 2048 + growr];
        }

        if (tid < 64) {
            float s = pre_v;
#pragma unroll
            for (int c = 0; c < 32; ++c) s += zz[tid][c];
            // gather the 4 gate pre-activations for unit lj within wave 0
            const int lj = tid & 15;
            const float zi = __shfl(s, lj, 64);
            const float zf = __shfl(s, lj + 16, 64);
            const float zg = __shfl(s, lj + 32, 64);
            const float zo = __shfl(s, lj + 48, 64);
            if (tid < UPS) {
                const float ig = sigf(zi), fg = sigf(zf), og = sigf(zo);
                c_state = fg * c_state + ig * tanhfast(zg);
                const float h = og * tanhfast(c_state);
                out[(size_t)tt * 1024 + dir * HID + slot * UPS + lj] = h;
                if (not_last) {
                    const float off = 3.f + 6.f * (float)((t >> 1) & 1);
                    __hip_atomic_store(hb0 + (t & 1) * HID + slot * UPS + lj, h + off,
                                       __ATOMIC_RELAXED, __HIP_MEMORY_SCOPE_AGENT);
                }
            }
        }

        if (not_last) {
            if (tid < HID) {
                const float lo = 2.f + 6.f * (float)((t >> 1) & 1);
                const float hi = lo + 2.f;
                const float* src = hb0 + (t & 1) * HID + tid;
                float v;
                do {
                    v = __hip_atomic_load(src, __ATOMIC_RELAXED,
                                          __HIP_MEMORY_SCOPE_AGENT);
                } while (!(v >= lo && v <= hi));
                h_sm[tid] = v - (lo + 1.f);
            }
            __syncthreads();
        }
        pre_v = pre_next;
    }
}

// ---------------- emissions: EM[4096,24] = X2[4096,1024] @ Wo[24,1024]^T + bo ----------------
__global__ __launch_bounds__(256)
void emissions_kernel(const float* __restrict__ X, const float* __restrict__ Wo,
                      const float* __restrict__ bo, float* __restrict__ EM)
{
    __shared__ float xs[1024];
    __shared__ float red[NT][9];
    const int t = blockIdx.x, tid = threadIdx.x;
    for (int i = tid; i < 1024; i += 256) xs[i] = X[(size_t)t * 1024 + i];
    __syncthreads();
    const int col = tid >> 3, s = tid & 7;
    if (col < NT) {
        float acc = 0.f;
        const float* wr = Wo + (size_t)col * 1024 + s * 128;
        const float* xp = xs + s * 128;
#pragma unroll 8
        for (int i = 0; i < 128; ++i) acc += wr[i] * xp[i];
        red[col][s] = acc;
    }
    __syncthreads();
    if (tid < NT) {
        float rsum = 0.f;
#pragma unroll
        for (int s2 = 0; s2 < 8; ++s2) rsum += red[tid][s2];
        EM[t * NT + tid] = rsum + bo[tid];
    }
}

// ---------------- numerator ----------------
__global__ __launch_bounds__(256)
void num_kernel(const float* __restrict__ EM, const int* __restrict__ tags,
                const float* __restrict__ stt, const float* __restrict__ ent,
                const float* __restrict__ tr, float* __restrict__ numout)
{
    __shared__ float red[256];
    const int tid = threadIdx.x;
    float acc = 0.f;
    for (int t = tid; t < SEQ; t += 256) {
        const int tg = tags[t];
        acc += EM[t * NT + tg];
        if (t < SEQ - 1) acc += tr[tg * NT + tags[t + 1]];
    }
    red[tid] = acc; __syncthreads();
    for (int s = 128; s > 0; s >>= 1) { if (tid < s) red[tid] += red[tid + s]; __syncthreads(); }
    if (tid == 0) numout[0] = red[0] + stt[tags[0]] + ent[tags[SEQ - 1]];
}

// ---------------- CRF stage 1: chunk products of M_t (t=1..4095), 16 per chunk ----------------
__global__ __launch_bounds__(576)
void crf_stage1(const float* __restrict__ EM, const float* __restrict__ trans,
                float* __restrict__ CH)
{
    __shared__ float tr[NT][NT];
    __shared__ float cur[2][NT][NT + 1];
    const int tid = threadIdx.x;
    const int i = tid / NT, j = tid % NT;
    const int c = blockIdx.x;
    const int t0 = 1 + c * 16;
    const int cm = min(16, SEQ - t0);
    const float trv = trans[i * NT + j];
    tr[i][j] = trv;
    cur[0][i][j] = trv + EM[t0 * NT + j];
    __syncthreads();
    int pp = 0;
    for (int s = 1; s < cm; ++s) {
        const float e = EM[(t0 + s) * NT + j];
        float m = -1e30f;
#pragma unroll
        for (int k = 0; k < NT; ++k) m = fmaxf(m, cur[pp][i][k] + tr[k][j]);
        float sum = 0.f;
#pragma unroll
        for (int k = 0; k < NT; ++k) sum += __expf(cur[pp][i][k] + tr[k][j] - m);
        cur[1 - pp][i][j] = m + __logf(sum) + e;
        pp = 1 - pp;
        __syncthreads();
    }
    CH[(size_t)c * 576 + i * NT + j] = cur[pp][i][j];
}

// ---------------- CRF combine ----------------
__global__ __launch_bounds__(576)
void crf_combine(const float* __restrict__ IN, float* __restrict__ OUT, int per)
{
    __shared__ float cur[2][NT][NT + 1];
    const int tid = threadIdx.x;
    const int i = tid / NT, j = tid % NT;
    const int c = blockIdx.x;
    const float* base = IN + (size_t)c * per * 576;
    cur[0][i][j] = base[i * NT + j];
    __syncthreads();
    int pp = 0;
    for (int s = 1; s < per; ++s) {
        const float* B = base + (size_t)s * 576;
        float m = -1e30f;
#pragma unroll
        for (int k = 0; k < NT; ++k) m = fmaxf(m, cur[pp][i][k] + B[k * NT + j]);
        float sum = 0.f;
#pragma unroll
        for (int k = 0; k < NT; ++k) sum += __expf(cur[pp][i][k] + B[k * NT + j] - m);
        cur[1 - pp][i][j] = m + __logf(sum);
        pp = 1 - pp;
        __syncthreads();
    }
    OUT[(size_t)c * 576 + i * NT + j] = cur[pp][i][j];
}

// ---------------- CRF final ----------------
__global__ __launch_bounds__(576)
void crf_final(const float* __restrict__ P2, const float* __restrict__ EM,
               const float* __restrict__ stt, const float* __restrict__ ent,
               const float* __restrict__ numptr, float* __restrict__ outp)
{
    __shared__ float cur[2][NT][NT + 1];
    __shared__ float red[1024];
    const int tid = threadIdx.x;
    const int i = tid / NT, j = tid % NT;
    cur[0][i][j] = P2[i * NT + j];
    __syncthreads();
    int pp = 0;
    for (int s = 1; s < 16; ++s) {
        const float* B = P2 + (size_t)s * 576;
        float m = -1e30f;
#pragma unroll
        for (int k = 0; k < NT; ++k) m = fmaxf(m, cur[pp][i][k] + B[k * NT + j]);
        float sum = 0.f;
#pragma unroll
        for (int k = 0; k < NT; ++k) sum += __expf(cur[pp][i][k] + B[k * NT + j] - m);
        cur[1 - pp][i][j] = m + __logf(sum);
        pp = 1 - pp;
        __syncthreads();
    }
    const float v = stt[i] + EM[i] + cur[pp][i][j] + ent[j];
    red[tid] = v;
    for (int t2 = tid + 576; t2 < 1024; t2 += 576) red[t2] = -1e30f;
    __syncthreads();
    for (int s2 = 512; s2 > 0; s2 >>= 1) {
        if (tid < s2) red[tid] = fmaxf(red[tid], red[tid + s2]);
        __syncthreads();
    }
    const float m = red[0];
    __syncthreads();
    red[tid] = __expf(v - m);
    for (int t2 = tid + 576; t2 < 1024; t2 += 576) red[t2] = 0.f;
    __syncthreads();
    for (int s2 = 512; s2 > 0; s2 >>= 1) {
        if (tid < s2) red[tid] += red[tid + s2];
        __syncthreads();
    }
    if (tid == 0) outp[0] = m + __logf(red[0]) - numptr[0];
}

// ---------------- launcher ----------------
extern "C" void kernel_launch(void* const* d_in, const int* in_sizes, int n_in,
                              void* d_out, int out_size, void* d_ws, size_t ws_size,
                              hipStream_t stream)
{
    const float* emb    = (const float*)d_in[0];
    const float* wih0f  = (const float*)d_in[1];
    const float* whh0f  = (const float*)d_in[2];
    const float* b0f    = (const float*)d_in[3];
    const float* wih0b  = (const float*)d_in[4];
    const float* whh0b  = (const float*)d_in[5];
    const float* b0b    = (const float*)d_in[6];
    const float* wih1f  = (const float*)d_in[7];
    const float* whh1f  = (const float*)d_in[8];
    const float* b1f    = (const float*)d_in[9];
    const float* wih1b  = (const float*)d_in[10];
    const float* whh1b  = (const float*)d_in[11];
    const float* b1b    = (const float*)d_in[12];
    const float* wout   = (const float*)d_in[13];
    const float* bout   = (const float*)d_in[14];
    const float* sttr   = (const float*)d_in[15];
    const float* entr   = (const float*)d_in[16];
    const float* trans  = (const float*)d_in[17];
    const int*   sent   = (const int*)d_in[18];
    const int*   tags   = (const int*)d_in[19];

    float* ws = (float*)d_ws;
    float* X0   = ws;                          // 4096*300
    float* PRE  = X0 + 1228800;                // 2 * 4096*2048
    float* X1   = PRE + 16777216;              // 4096*1024
    float* X2   = X1 + 4194304;                // 4096*1024
    float* EMb  = X2 + 4194304;                // 4096*24
    float* CH   = EMb + 98304;                 // 256*576
    float* P2   = CH + 147456;                 // 16*576
    float* NUMv = P2 + 9216;                   // 1 (padded 64)
    float* HBUF = NUMv + 64;                   // 2 layers x (2 dirs x 2 bufs x 512)

    const int PREST = 8388608; // per-direction stride in PRE

    init_gather<<<4096, 64, 0, stream>>>(emb, sent, X0);

    dim3 gg(16, 32);
    sgemm_bias<<<gg, 256, 0, stream>>>(X0, wih0f, b0f, PRE,         4096, 2048, 300);
    sgemm_bias<<<gg, 256, 0, stream>>>(X0, wih0b, b0b, PRE + PREST, 4096, 2048, 300);
    lstm_rec<<<2 * RK, RTH, 0, stream>>>(PRE, PRE + PREST, whh0f, whh0b, X1, HBUF);

    sgemm_bias<<<gg, 256, 0, stream>>>(X1, wih1f, b1f, PRE,         4096, 2048, 1024);
    sgemm_bias<<<gg, 256, 0, stream>>>(X1, wih1b, b1b, PRE + PREST, 4096, 2048, 1024);
    lstm_rec<<<2 * RK, RTH, 0, stream>>>(PRE, PRE + PREST, whh1f, whh1b, X2, HBUF + 2048);

    emissions_kernel<<<4096, 256, 0, stream>>>(X2, wout, bout, EMb);
    num_kernel<<<1, 256, 0, stream>>>(EMb, tags, sttr, entr, trans, NUMv);
    crf_stage1<<<256, 576, 0, stream>>>(EMb, trans, CH);
    crf_combine<<<16, 576, 0, stream>>>(CH, P2, 16);
    crf_final<<<1, 576, 0, stream>>>(P2, EMb, sttr, entr, NUMv, (float*)d_out);
}

// Round 6
// 16254.938 us; speedup vs baseline: 2.2334x; 1.0208x over previous
//
#include <hip/hip_runtime.h>

#define RK 32          // workgroups per LSTM direction
#define RTH 1024       // threads per recurrence WG
#define UPS 16         // hidden units per slot (512/RK)
#define SEQ 4096
#define HID 512
#define NT 24

__device__ __forceinline__ float sigf(float x) { return 1.f / (1.f + __expf(-x)); }
__device__ __forceinline__ float tanhfast(float x) {
    const float e = __expf(2.f * x);
    return 1.f - 2.f / (e + 1.f);
}

// 16B load that bypasses L1/L2 (system-coherent) -> reads the L3/mall
// coherence point that agent-scope atomic stores write through to.
__device__ __forceinline__ float4 load_f4_cc(const float* p) {
    float4 v;
    asm volatile("global_load_dwordx4 %0, %1, off sc0 sc1\n\ts_waitcnt vmcnt(0)"
                 : "=v"(v) : "v"(p) : "memory");
    return v;
}

// ---------------- init: embedding gather ----------------
__global__ __launch_bounds__(64)
void init_gather(const float* __restrict__ emb, const int* __restrict__ sent,
                 float* __restrict__ X0)
{
    const int b = blockIdx.x, tid = threadIdx.x;
    const size_t row = (size_t)sent[b] * 300;
    for (int e = tid; e < 300; e += 64)
        X0[(size_t)b * 300 + e] = emb[row + e];
}

// ---------------- fp32 GEMM: C[M,N] = A[M,K] @ W[N,K]^T + bias[N] ----------------
__global__ __launch_bounds__(256)
void sgemm_bias(const float* __restrict__ A, const float* __restrict__ W,
                const float* __restrict__ bias, float* __restrict__ C,
                int M, int N, int K)
{
    __shared__ float As[8][128];
    __shared__ float Ws[8][128];
    const int tid = threadIdx.x;
    const int m0 = blockIdx.y * 128, n0 = blockIdx.x * 128;
    const int tx = tid & 15, ty = tid >> 4;
    const int lr = tid >> 1, lk = (tid & 1) * 4;
    float acc[8][8] = {};
    for (int k0 = 0; k0 < K; k0 += 8) {
#pragma unroll
        for (int u = 0; u < 4; ++u) {
            const int k = k0 + lk + u;
            As[lk + u][lr] = (k < K) ? A[(size_t)(m0 + lr) * K + k] : 0.f;
            Ws[lk + u][lr] = (k < K) ? W[(size_t)(n0 + lr) * K + k] : 0.f;
        }
        __syncthreads();
#pragma unroll
        for (int kk = 0; kk < 8; ++kk) {
            float a[8], b[8];
#pragma unroll
            for (int i = 0; i < 8; ++i) a[i] = As[kk][ty * 8 + i];
#pragma unroll
            for (int i = 0; i < 8; ++i) b[i] = Ws[kk][tx * 8 + i];
#pragma unroll
            for (int i = 0; i < 8; ++i)
#pragma unroll
                for (int j = 0; j < 8; ++j) acc[i][j] += a[i] * b[j];
        }
        __syncthreads();
    }
#pragma unroll
    for (int i = 0; i < 8; ++i) {
        const int m = m0 + ty * 8 + i;
#pragma unroll
        for (int j = 0; j < 8; ++j) {
            const int n = n0 + tx * 8 + j;
            C[(size_t)m * N + n] = acc[i][j] + bias[n];
        }
    }
}

// ---------------- LSTM recurrence, v6 ----------------
// 2*RK=64 WGs x 1024 thr. dir = blockIdx&1. Double-buffered self-validating
// h+offset exchange (skew<=1 proof: a WG enters step t+1 only after all WGs
// stored h_t, so no lap/overwrite race; stale-phase collision needs skew 4).
// v6: 16B sc0sc1 polls by 128 thr/WG (4x less L3 contention); weights pinned
// loop-carried in VGPRs via in-loop volatile asm (v5's VGPR=32 proved the
// pre-loop pin failed and W was reloaded every step on the critical path).
__global__ __launch_bounds__(RTH, 1)
void lstm_rec(const float* __restrict__ pre_f, const float* __restrict__ pre_b,
              const float* __restrict__ whh_f, const float* __restrict__ whh_b,
              float* __restrict__ out,           // (4096 x 1024): fwd [0,512), bwd [512,1024)
              float* __restrict__ hbuf)          // this layer: 2 dirs x 2 bufs x 512
{
    const int g = blockIdx.x;
    const int dir = g & 1, slot = g >> 1;
    const float* pre = dir ? pre_b : pre_f;
    const float* whh = dir ? whh_b : whh_f;
    float* hb0 = hbuf + dir * 2 * HID;     // + (t&1)*HID selects the buffer

    const int tid = threadIdx.x;
    const int seg = tid >> 5;        // 0..31 (16-col segment)
    const int rsub = tid & 31;       // 0..31

    // local row r = k*16 + j (k=gate, j=unit); global z-row = gate*512 + slot*16 + j
    const int k0g = rsub >> 4, j0 = rsub & 15;
    const int grow0 = k0g * HID + slot * UPS + j0;
    const int grow1 = (k0g + 2) * HID + slot * UPS + j0;

    float4 w0[4], w1[4];
    {
        const float4* p0 = (const float4*)(whh + (size_t)grow0 * HID + seg * 16);
        const float4* p1 = (const float4*)(whh + (size_t)grow1 * HID + seg * 16);
#pragma unroll
        for (int c = 0; c < 4; ++c) { w0[c] = p0[c]; w1[c] = p1[c]; }
    }

    // reducer-lane (tid<64) row mapping
    const int rr = tid & 63;
    const int growr = (rr >> 4) * HID + slot * UPS + (rr & 15);

    __shared__ float h_sm[HID];
    __shared__ float zz[64][33];
    float c_state = 0.f;

    if (tid < HID) h_sm[tid] = 0.f;
    __syncthreads();

    float pre_v = 0.f;
    if (tid < 64) pre_v = pre[(size_t)(dir ? (SEQ - 1) : 0) * 2048 + growr];

    for (int t = 0; t < SEQ; ++t) {
        const int tt = dir ? (SEQ - 1 - t) : t;
        const bool not_last = (t + 1 < SEQ);

        // loop-carried VGPR pin: volatile asm cannot be re-executed, so the
        // compiler must keep all 32 weight floats live across iterations.
        asm volatile("" : "+v"(w0[0].x), "+v"(w0[0].y), "+v"(w0[0].z), "+v"(w0[0].w),
                           "+v"(w0[1].x), "+v"(w0[1].y), "+v"(w0[1].z), "+v"(w0[1].w),
                           "+v"(w0[2].x), "+v"(w0[2].y), "+v"(w0[2].z), "+v"(w0[2].w),
                           "+v"(w0[3].x), "+v"(w0[3].y), "+v"(w0[3].z), "+v"(w0[3].w));
        asm volatile("" : "+v"(w1[0].x), "+v"(w1[0].y), "+v"(w1[0].z), "+v"(w1[0].w),
                           "+v"(w1[1].x), "+v"(w1[1].y), "+v"(w1[1].z), "+v"(w1[1].w),
                           "+v"(w1[2].x), "+v"(w1[2].y), "+v"(w1[2].z), "+v"(w1[2].w),
                           "+v"(w1[3].x), "+v"(w1[3].y), "+v"(w1[3].z), "+v"(w1[3].w));

        // dot: 2 local rows x 16 cols against h_sm[seg*16 ..]
        const float4* hp = (const float4*)(h_sm + seg * 16);
        const float4 h0 = hp[0], h1 = hp[1], h2 = hp[2], h3 = hp[3];
        float a0, a1;
        {
            a0  = w0[0].x*h0.x + w0[0].y*h0.y + w0[0].z*h0.z + w0[0].w*h0.w;
            a0 += w0[1].x*h1.x + w0[1].y*h1.y + w0[1].z*h1.z + w0[1].w*h1.w;
            a0 += w0[2].x*h2.x + w0[2].y*h2.y + w0[2].z*h2.z + w0[2].w*h2.w;
            a0 += w0[3].x*h3.x + w0[3].y*h3.y + w0[3].z*h3.z + w0[3].w*h3.w;
            a1  = w1[0].x*h0.x + w1[0].y*h0.y + w1[0].z*h0.z + w1[0].w*h0.w;
            a1 += w1[1].x*h1.x + w1[1].y*h1.y + w1[1].z*h1.z + w1[1].w*h1.w;
            a1 += w1[2].x*h2.x + w1[2].y*h2.y + w1[2].z*h2.z + w1[2].w*h2.w;
            a1 += w1[3].x*h3.x + w1[3].y*h3.y + w1[3].z*h3.z + w1[3].w*h3.w;
        }
        zz[rsub][seg] = a0;
        zz[rsub + 32][seg] = a1;
        __syncthreads();

        // prefetch next step's pre (latency hidden under the exchange)
        float pre_next = 0.f;
        if (tid < 64 && not_last) {
            const int tn = dir ? (SEQ - 2 - t) : (t + 1);
            pre_next = pre[(size_t)tn * 2048 + growr];
        }

        if (tid < 64) {
            float s = pre_v;
#pragma unroll
            for (int c = 0; c < 32; ++c) s += zz[tid][c];
            // gather the 4 gate pre-activations for unit lj within wave 0
            const int lj = tid & 15;
            const float zi = __shfl(s, lj, 64);
            const float zf = __shfl(s, lj + 16, 64);
            const float zg = __shfl(s, lj + 32, 64);
            const float zo = __shfl(s, lj + 48, 64);
            if (tid < UPS) {
                const float ig = sigf(zi), fg = sigf(zf), og = sigf(zo);
                c_state = fg * c_state + ig * tanhfast(zg);
                const float h = og * tanhfast(c_state);
                out[(size_t)tt * 1024 + dir * HID + slot * UPS + lj] = h;
                if (not_last) {
                    const float off = 3.f + 6.f * (float)((t >> 1) & 1);
                    __hip_atomic_store(hb0 + (t & 1) * HID + slot * UPS + lj, h + off,
                                       __ATOMIC_RELAXED, __HIP_MEMORY_SCOPE_AGENT);
                }
            }
        }

        if (not_last) {
            if (tid < 128) {
                const float lo = 2.f + 6.f * (float)((t >> 1) & 1);
                const float hi = lo + 2.f;
                const float mid = lo + 1.f;
                const float* src = hb0 + (t & 1) * HID + tid * 4;
                float4 v;
                for (;;) {
                    v = load_f4_cc(src);
                    if (v.x >= lo && v.x <= hi && v.y >= lo && v.y <= hi &&
                        v.z >= lo && v.z <= hi && v.w >= lo && v.w <= hi) break;
                }
                float4* dst = (float4*)(h_sm + tid * 4);
                *dst = make_float4(v.x - mid, v.y - mid, v.z - mid, v.w - mid);
            }
            __syncthreads();
        }
        pre_v = pre_next;
    }
}

// ---------------- emissions: EM[4096,24] = X2[4096,1024] @ Wo[24,1024]^T + bo ----------------
__global__ __launch_bounds__(256)
void emissions_kernel(const float* __restrict__ X, const float* __restrict__ Wo,
                      const float* __restrict__ bo, float* __restrict__ EM)
{
    __shared__ float xs[1024];
    __shared__ float red[NT][9];
    const int t = blockIdx.x, tid = threadIdx.x;
    for (int i = tid; i < 1024; i += 256) xs[i] = X[(size_t)t * 1024 + i];
    __syncthreads();
    const int col = tid >> 3, s = tid & 7;
    if (col < NT) {
        float acc = 0.f;
        const float* wr = Wo + (size_t)col * 1024 + s * 128;
        const float* xp = xs + s * 128;
#pragma unroll 8
        for (int i = 0; i < 128; ++i) acc += wr[i] * xp[i];
        red[col][s] = acc;
    }
    __syncthreads();
    if (tid < NT) {
        float rsum = 0.f;
#pragma unroll
        for (int s2 = 0; s2 < 8; ++s2) rsum += red[tid][s2];
        EM[t * NT + tid] = rsum + bo[tid];
    }
}

// ---------------- numerator ----------------
__global__ __launch_bounds__(256)
void num_kernel(const float* __restrict__ EM, const int* __restrict__ tags,
                const float* __restrict__ stt, const float* __restrict__ ent,
                const float* __restrict__ tr, float* __restrict__ numout)
{
    __shared__ float red[256];
    const int tid = threadIdx.x;
    float acc = 0.f;
    for (int t = tid; t < SEQ; t += 256) {
        const int tg = tags[t];
        acc += EM[t * NT + tg];
        if (t < SEQ - 1) acc += tr[tg * NT + tags[t + 1]];
    }
    red[tid] = acc; __syncthreads();
    for (int s = 128; s > 0; s >>= 1) { if (tid < s) red[tid] += red[tid + s]; __syncthreads(); }
    if (tid == 0) numout[0] = red[0] + stt[tags[0]] + ent[tags[SEQ - 1]];
}

// ---------------- CRF stage 1: chunk products of M_t (t=1..4095), 16 per chunk ----------------
__global__ __launch_bounds__(576)
void crf_stage1(const float* __restrict__ EM, const float* __restrict__ trans,
                float* __restrict__ CH)
{
    __shared__ float tr[NT][NT];
    __shared__ float cur[2][NT][NT + 1];
    const int tid = threadIdx.x;
    const int i = tid / NT, j = tid % NT;
    const int c = blockIdx.x;
    const int t0 = 1 + c * 16;
    const int cm = min(16, SEQ - t0);
    const float trv = trans[i * NT + j];
    tr[i][j] = trv;
    cur[0][i][j] = trv + EM[t0 * NT + j];
    __syncthreads();
    int pp = 0;
    for (int s = 1; s < cm; ++s) {
        const float e = EM[(t0 + s) * NT + j];
        float m = -1e30f;
#pragma unroll
        for (int k = 0; k < NT; ++k) m = fmaxf(m, cur[pp][i][k] + tr[k][j]);
        float sum = 0.f;
#pragma unroll
        for (int k = 0; k < NT; ++k) sum += __expf(cur[pp][i][k] + tr[k][j] - m);
        cur[1 - pp][i][j] = m + __logf(sum) + e;
        pp = 1 - pp;
        __syncthreads();
    }
    CH[(size_t)c * 576 + i * NT + j] = cur[pp][i][j];
}

// ---------------- CRF combine ----------------
__global__ __launch_bounds__(576)
void crf_combine(const float* __restrict__ IN, float* __restrict__ OUT, int per)
{
    __shared__ float cur[2][NT][NT + 1];
    const int tid = threadIdx.x;
    const int i = tid / NT, j = tid % NT;
    const int c = blockIdx.x;
    const float* base = IN + (size_t)c * per * 576;
    cur[0][i][j] = base[i * NT + j];
    __syncthreads();
    int pp = 0;
    for (int s = 1; s < per; ++s) {
        const float* B = base + (size_t)s * 576;
        float m = -1e30f;
#pragma unroll
        for (int k = 0; k < NT; ++k) m = fmaxf(m, cur[pp][i][k] + B[k * NT + j]);
        float sum = 0.f;
#pragma unroll
        for (int k = 0; k < NT; ++k) sum += __expf(cur[pp][i][k] + B[k * NT + j] - m);
        cur[1 - pp][i][j] = m + __logf(sum);
        pp = 1 - pp;
        __syncthreads();
    }
    OUT[(size_t)c * 576 + i * NT + j] = cur[pp][i][j];
}

// ---------------- CRF final ----------------
__global__ __launch_bounds__(576)
void crf_final(const float* __restrict__ P2, const float* __restrict__ EM,
               const float* __restrict__ stt, const float* __restrict__ ent,
               const float* __restrict__ numptr, float* __restrict__ outp)
{
    __shared__ float cur[2][NT][NT + 1];
    __shared__ float red[1024];
    const int tid = threadIdx.x;
    const int i = tid / NT, j = tid % NT;
    cur[0][i][j] = P2[i * NT + j];
    __syncthreads();
    int pp = 0;
    for (int s = 1; s < 16; ++s) {
        const float* B = P2 + (size_t)s * 576;
        float m = -1e30f;
#pragma unroll
        for (int k = 0; k < NT; ++k) m = fmaxf(m, cur[pp][i][k] + B[k * NT + j]);
        float sum = 0.f;
#pragma unroll
        for (int k = 0; k < NT; ++k) sum += __expf(cur[pp][i][k] + B[k * NT + j] - m);
        cur[1 - pp][i][j] = m + __logf(sum);
        pp = 1 - pp;
        __syncthreads();
    }
    const float v = stt[i] + EM[i] + cur[pp][i][j] + ent[j];
    red[tid] = v;
    for (int t2 = tid + 576; t2 < 1024; t2 += 576) red[t2] = -1e30f;
    __syncthreads();
    for (int s2 = 512; s2 > 0; s2 >>= 1) {
        if (tid < s2) red[tid] = fmaxf(red[tid], red[tid + s2]);
        __syncthreads();
    }
    const float m = red[0];
    __syncthreads();
    red[tid] = __expf(v - m);
    for (int t2 = tid + 576; t2 < 1024; t2 += 576) red[t2] = 0.f;
    __syncthreads();
    for (int s2 = 512; s2 > 0; s2 >>= 1) {
        if (tid < s2) red[tid] += red[tid + s2];
        __syncthreads();
    }
    if (tid == 0) outp[0] = m + __logf(red[0]) - numptr[0];
}

// ---------------- launcher ----------------
extern "C" void kernel_launch(void* const* d_in, const int* in_sizes, int n_in,
                              void* d_out, int out_size, void* d_ws, size_t ws_size,
                              hipStream_t stream)
{
    const float* emb    = (const float*)d_in[0];
    const float* wih0f  = (const float*)d_in[1];
    const float* whh0f  = (const float*)d_in[2];
    const float* b0f    = (const float*)d_in[3];
    const float* wih0b  = (const float*)d_in[4];
    const float* whh0b  = (const float*)d_in[5];
    const float* b0b    = (const float*)d_in[6];
    const float* wih1f  = (const float*)d_in[7];
    const float* whh1f  = (const float*)d_in[8];
    const float* b1f    = (const float*)d_in[9];
    const float* wih1b  = (const float*)d_in[10];
    const float* whh1b  = (const float*)d_in[11];
    const float* b1b    = (const float*)d_in[12];
    const float* wout   = (const float*)d_in[13];
    const float* bout   = (const float*)d_in[14];
    const float* sttr   = (const float*)d_in[15];
    const float* entr   = (const float*)d_in[16];
    const float* trans  = (const float*)d_in[17];
    const int*   sent   = (const int*)d_in[18];
    const int*   tags   = (const int*)d_in[19];

    float* ws = (float*)d_ws;
    float* X0   = ws;                          // 4096*300
    float* PRE  = X0 + 1228800;                // 2 * 4096*2048
    float* X1   = PRE + 16777216;              // 4096*1024
    float* X2   = X1 + 4194304;                // 4096*1024
    float* EMb  = X2 + 4194304;                // 4096*24
    float* CH   = EMb + 98304;                 // 256*576
    float* P2   = CH + 147456;                 // 16*576
    float* NUMv = P2 + 9216;                   // 1 (padded 64)
    float* HBUF = NUMv + 64;                   // 2 layers x (2 dirs x 2 bufs x 512)

    const int PREST = 8388608; // per-direction stride in PRE

    init_gather<<<4096, 64, 0, stream>>>(emb, sent, X0);

    dim3 gg(16, 32);
    sgemm_bias<<<gg, 256, 0, stream>>>(X0, wih0f, b0f, PRE,         4096, 2048, 300);
    sgemm_bias<<<gg, 256, 0, stream>>>(X0, wih0b, b0b, PRE + PREST, 4096, 2048, 300);
    lstm_rec<<<2 * RK, RTH, 0, stream>>>(PRE, PRE + PREST, whh0f, whh0b, X1, HBUF);

    sgemm_bias<<<gg, 256, 0, stream>>>(X1, wih1f, b1f, PRE,         4096, 2048, 1024);
    sgemm_bias<<<gg, 256, 0, stream>>>(X1, wih1b, b1b, PRE + PREST, 4096, 2048, 1024);
    lstm_rec<<<2 * RK, RTH, 0, stream>>>(PRE, PRE + PREST, whh1f, whh1b, X2, HBUF + 2048);

    emissions_kernel<<<4096, 256, 0, stream>>>(X2, wout, bout, EMb);
    num_kernel<<<1, 256, 0, stream>>>(EMb, tags, sttr, entr, trans, NUMv);
    crf_stage1<<<256, 576, 0, stream>>>(EMb, trans, CH);
    crf_combine<<<16, 576, 0, stream>>>(CH, P2, 16);
    crf_final<<<1, 576, 0, stream>>>(P2, EMb, sttr, entr, NUMv, (float*)d_out);
}